// Round 9
// baseline (36.389 us; speedup 1.0000x reference)
//
#include <hip/hip_runtime.h>

// 16 x 8 x 512 x 512 fp32; 2x2 grey opening + MSE (scalar out)
// R6 structure (row-pair depth-2 ring, CHUNK=32) + NON-TEMPORAL loads:
// probe whether the ~4.3 TB/s read plateau is cache-insertion throttling.
#define IMG_H 512
#define IMG_W 512
#define NIMG 128
#define CHUNK 32
#define NCHUNK (IMG_H / CHUNK)          // 16
#define THREADS 256
#define WPB (THREADS / 64)              // 4 waves / block
#define NBLOCKS (NIMG * NCHUNK / WPB)   // 512

typedef float f4v __attribute__((ext_vector_type(4)));

__global__ __launch_bounds__(THREADS)
void opening_mse_kernel(const float* __restrict__ X, float* __restrict__ out) {
    const int lane = threadIdx.x & 63;
    const int gw   = blockIdx.x * WPB + (threadIdx.x >> 6);
    const int n     = gw >> 4;               // image 0..127
    const int chunk = gw & (NCHUNK - 1);     // 0..15
    const int s = chunk * CHUNK;
    const int e = s + CHUNK;                 // output rows [s, e)
    const float* __restrict__ img = X + (size_t)n * (IMG_H * IMG_W);
    const int cb = lane << 3;                // 8 cols/lane; wave spans 512 cols
    const int rmax = (e < IMG_H) ? e : (IMG_H - 1);   // overshoot clamp

    // non-temporal (evict-first) streaming loads
    auto ld = [&](int r, f4v& a, f4v& b) {
        const f4v* p = reinterpret_cast<const f4v*>(img + (size_t)r * IMG_W + cb);
        a = __builtin_nontemporal_load(p);
        b = __builtin_nontemporal_load(p + 1);
    };

    // h[k] = min(x[c-1], x[c]) for c = cb+k, k=0..8; h[8] is the dilation's
    // right-neighbor column (lane 63: h[8]=h[7] == reflect clamp at col 511).
    auto mkh = [&](const f4v& a, const f4v& b, float (&h)[9]) {
        float xl = __shfl_up(b[3], 1, 64);
        if (lane == 0) xl = a[0];
        float xr = __shfl_down(a[0], 1, 64);
        h[0] = fminf(xl, a[0]);
        h[1] = fminf(a[0], a[1]);
        h[2] = fminf(a[1], a[2]);
        h[3] = fminf(a[2], a[3]);
        h[4] = fminf(a[3], b[0]);
        h[5] = fminf(b[0], b[1]);
        h[6] = fminf(b[1], b[2]);
        h[7] = fminf(b[2], b[3]);
        h[8] = (lane == 63) ? h[7] : fminf(b[3], xr);
    };

    float hprev[9], hd[8];
    f4v xa, xb;   // x of the row whose opened value we emit next

    {   // prime: h(row s-1 clamped), h(row s), hd[s]
        f4v ta, tb;
        ld(s > 0 ? s - 1 : 0, ta, tb);
        mkh(ta, tb, hprev);
        ld(s, xa, xb);
        float hcur[9], E[9];
        mkh(xa, xb, hcur);
        #pragma unroll
        for (int k = 0; k < 9; ++k) E[k] = fminf(hprev[k], hcur[k]);
        #pragma unroll
        for (int k = 0; k < 8; ++k) hd[k] = fmaxf(E[k], E[k + 1]);
        #pragma unroll
        for (int k = 0; k < 9; ++k) hprev[k] = hcur[k];
    }

    // depth-2 ring of ROW PAIRS: 4 rows (8 KB/wave) in flight
    f4v q1a0, q1b0, q1a1, q1b1;
    f4v q2a0, q2b0, q2a1, q2b1;
    ld(s + 1, q1a0, q1b0);
    ld(s + 2, q1a1, q1b1);
    ld(s + 3, q2a0, q2b0);
    ld(s + 4, q2a1, q2b1);           // s+4 <= 484 < IMG_H always

    float acc = 0.0f;
    #pragma unroll 2
    for (int t = 0; t < CHUNK / 2; ++t) {
        const int a0 = s + 1 + 2 * t;
        const int a1 = a0 + 1;

        f4v c0a = q1a0, c0b = q1b0, c1a = q1a1, c1b = q1b1;
        q1a0 = q2a0; q1b0 = q2b0; q1a1 = q2a1; q1b1 = q2b1;
        int r0 = a0 + 4; r0 = r0 < rmax ? r0 : rmax;
        int r1 = a0 + 5; r1 = r1 < rmax ? r1 : rmax;
        ld(r0, q2a0, q2b0);
        ld(r1, q2a1, q2b1);

        // ---- row a0 (always < IMG_H since a0 <= s+31 <= 511)
        float h0[9], hd0[8];
        {
            float E[9];
            mkh(c0a, c0b, h0);
            #pragma unroll
            for (int k = 0; k < 9; ++k) E[k] = fminf(hprev[k], h0[k]);
            #pragma unroll
            for (int k = 0; k < 8; ++k) hd0[k] = fmaxf(E[k], E[k + 1]);
        }
        {   // opened(a0-1) = max(hd, hd0) vs xa/xb
            float d;
            d = xa[0] - fmaxf(hd[0], hd0[0]); acc = fmaf(d, d, acc);
            d = xa[1] - fmaxf(hd[1], hd0[1]); acc = fmaf(d, d, acc);
            d = xa[2] - fmaxf(hd[2], hd0[2]); acc = fmaf(d, d, acc);
            d = xa[3] - fmaxf(hd[3], hd0[3]); acc = fmaf(d, d, acc);
            d = xb[0] - fmaxf(hd[4], hd0[4]); acc = fmaf(d, d, acc);
            d = xb[1] - fmaxf(hd[5], hd0[5]); acc = fmaf(d, d, acc);
            d = xb[2] - fmaxf(hd[6], hd0[6]); acc = fmaf(d, d, acc);
            d = xb[3] - fmaxf(hd[7], hd0[7]); acc = fmaf(d, d, acc);
        }

        // ---- row a1 (a1 == IMG_H only at t=15 of the last chunk)
        float h1[9], hd1[8];
        if (a1 < IMG_H) {
            float E[9];
            mkh(c1a, c1b, h1);
            #pragma unroll
            for (int k = 0; k < 9; ++k) E[k] = fminf(h0[k], h1[k]);
            #pragma unroll
            for (int k = 0; k < 8; ++k) hd1[k] = fmaxf(E[k], E[k + 1]);
            #pragma unroll
            for (int k = 0; k < 9; ++k) hprev[k] = h1[k];
        } else {
            #pragma unroll
            for (int k = 0; k < 8; ++k) hd1[k] = hd0[k];   // hd[H] := hd[H-1]
        }
        {   // opened(a1-1) = max(hd0, hd1) vs x(a0) = c0
            float d;
            d = c0a[0] - fmaxf(hd0[0], hd1[0]); acc = fmaf(d, d, acc);
            d = c0a[1] - fmaxf(hd0[1], hd1[1]); acc = fmaf(d, d, acc);
            d = c0a[2] - fmaxf(hd0[2], hd1[2]); acc = fmaf(d, d, acc);
            d = c0a[3] - fmaxf(hd0[3], hd1[3]); acc = fmaf(d, d, acc);
            d = c0b[0] - fmaxf(hd0[4], hd1[4]); acc = fmaf(d, d, acc);
            d = c0b[1] - fmaxf(hd0[5], hd1[5]); acc = fmaf(d, d, acc);
            d = c0b[2] - fmaxf(hd0[6], hd1[6]); acc = fmaf(d, d, acc);
            d = c0b[3] - fmaxf(hd0[7], hd1[7]); acc = fmaf(d, d, acc);
        }

        #pragma unroll
        for (int k = 0; k < 8; ++k) hd[k] = hd1[k];
        xa = c1a; xb = c1b;
    }

    // wave shuffle reduce -> LDS across 4 waves -> one atomic per block
    #pragma unroll
    for (int off = 32; off > 0; off >>= 1)
        acc += __shfl_down(acc, off, 64);

    __shared__ float wsum[WPB];
    const int wid = threadIdx.x >> 6;
    if (lane == 0) wsum[wid] = acc;
    __syncthreads();
    if (threadIdx.x == 0) {
        float sblk = wsum[0] + wsum[1] + wsum[2] + wsum[3];
        atomicAdd(out, sblk * (1.0f / 33554432.0f));   // / 2^25 -> mean
    }
}

extern "C" void kernel_launch(void* const* d_in, const int* in_sizes, int n_in,
                              void* d_out, int out_size, void* d_ws, size_t ws_size,
                              hipStream_t stream) {
    const float* X = (const float*)d_in[0];
    float* out = (float*)d_out;
    hipMemsetAsync(out, 0, sizeof(float), stream);
    opening_mse_kernel<<<NBLOCKS, THREADS, 0, stream>>>(X, out);
}

// Round 10
// 35.885 us; speedup vs baseline: 1.0140x; 1.0140x over previous
//
#include <hip/hip_runtime.h>

// 16 x 8 x 512 x 512 fp32; 2x2 grey opening + MSE (scalar out)
// Stream-count probe: CHUNK=64 -> 1024 waves, each streaming a contiguous
// ~132 KB region; depth-4 row-pair ring (8 rows / 16 KB in flight per wave).
#define IMG_H 512
#define IMG_W 512
#define NIMG 128
#define CHUNK 64
#define NCHUNK (IMG_H / CHUNK)          // 8
#define THREADS 128
#define WPB (THREADS / 64)              // 2 waves / block
#define NWAVES (NIMG * NCHUNK)          // 1024
#define NBLOCKS (NWAVES / WPB)          // 512 -> 2 blocks/CU, 4 waves/CU

__global__ __launch_bounds__(THREADS)
void opening_mse_kernel(const float* __restrict__ X, float* __restrict__ out) {
    const int lane = threadIdx.x & 63;
    const int wid  = threadIdx.x >> 6;
    const int gw   = blockIdx.x * WPB + wid;
    const int n     = gw >> 3;               // image 0..127
    const int chunk = gw & (NCHUNK - 1);     // 0..7
    const int s = chunk * CHUNK;
    const int e = s + CHUNK;                 // output rows [s, e)
    const float* __restrict__ img = X + (size_t)n * (IMG_H * IMG_W);
    const int cb = lane << 3;                // 8 cols/lane; wave spans 512 cols
    const int rmax = (e < IMG_H) ? e : (IMG_H - 1);   // overshoot clamp (L1 hit)

    auto ld = [&](int r, float4& a, float4& b) {
        const float* __restrict__ p = img + (size_t)r * IMG_W + cb;
        a = *reinterpret_cast<const float4*>(p);
        b = *reinterpret_cast<const float4*>(p + 4);
    };

    // h[k] = min(x[c-1], x[c]) for c = cb+k, k=0..8; h[8] is the dilation's
    // right-neighbor column (lane 63: h[8]=h[7] == reflect clamp at col 511).
    auto mkh = [&](const float4& a, const float4& b, float (&h)[9]) {
        float xl = __shfl_up(b.w, 1, 64);
        if (lane == 0) xl = a.x;
        float xr = __shfl_down(a.x, 1, 64);
        h[0] = fminf(xl, a.x);
        h[1] = fminf(a.x, a.y);
        h[2] = fminf(a.y, a.z);
        h[3] = fminf(a.z, a.w);
        h[4] = fminf(a.w, b.x);
        h[5] = fminf(b.x, b.y);
        h[6] = fminf(b.y, b.z);
        h[7] = fminf(b.z, b.w);
        h[8] = (lane == 63) ? h[7] : fminf(b.w, xr);
    };

    float hprev[9], hd[8];
    float4 xa, xb;   // x of the row whose opened value we emit next

    {   // prime: h(row s-1 clamped), h(row s), hd[s]
        float4 ta, tb;
        ld(s > 0 ? s - 1 : 0, ta, tb);
        mkh(ta, tb, hprev);
        ld(s, xa, xb);
        float hcur[9], E[9];
        #pragma unroll
        for (int k = 0; k < 9; ++k) hcur[k] = 0.0f;
        mkh(xa, xb, hcur);
        #pragma unroll
        for (int k = 0; k < 9; ++k) E[k] = fminf(hprev[k], hcur[k]);
        #pragma unroll
        for (int k = 0; k < 8; ++k) hd[k] = fmaxf(E[k], E[k + 1]);
        #pragma unroll
        for (int k = 0; k < 9; ++k) hprev[k] = hcur[k];
    }

    // depth-4 ring of ROW PAIRS: 8 rows (16 KB/wave) in flight. s+8 <= 456 ok.
    float4 r1a0, r1b0, r1a1, r1b1;
    float4 r2a0, r2b0, r2a1, r2b1;
    float4 r3a0, r3b0, r3a1, r3b1;
    float4 r4a0, r4b0, r4a1, r4b1;
    ld(s + 1, r1a0, r1b0);  ld(s + 2, r1a1, r1b1);
    ld(s + 3, r2a0, r2b0);  ld(s + 4, r2a1, r2b1);
    ld(s + 5, r3a0, r3b0);  ld(s + 6, r3a1, r3b1);
    ld(s + 7, r4a0, r4b0);  ld(s + 8, r4a1, r4b1);

    float acc = 0.0f;
    #pragma unroll 4
    for (int t = 0; t < CHUNK / 2; ++t) {
        const int a0 = s + 1 + 2 * t;
        const int a1 = a0 + 1;

        float4 c0a = r1a0, c0b = r1b0, c1a = r1a1, c1b = r1b1;
        r1a0 = r2a0; r1b0 = r2b0; r1a1 = r2a1; r1b1 = r2b1;
        r2a0 = r3a0; r2b0 = r3b0; r2a1 = r3a1; r2b1 = r3b1;
        r3a0 = r4a0; r3b0 = r4b0; r3a1 = r4a1; r3b1 = r4b1;
        int rp0 = a0 + 8; rp0 = rp0 < rmax ? rp0 : rmax;
        int rp1 = a0 + 9; rp1 = rp1 < rmax ? rp1 : rmax;
        ld(rp0, r4a0, r4b0);
        ld(rp1, r4a1, r4b1);

        // ---- row a0 (always < IMG_H since a0 <= s+63 <= 511)
        float h0[9], hd0[8];
        {
            float E[9];
            mkh(c0a, c0b, h0);
            #pragma unroll
            for (int k = 0; k < 9; ++k) E[k] = fminf(hprev[k], h0[k]);
            #pragma unroll
            for (int k = 0; k < 8; ++k) hd0[k] = fmaxf(E[k], E[k + 1]);
        }
        {   // opened(a0-1) = max(hd, hd0) vs xa/xb
            float d;
            d = xa.x - fmaxf(hd[0], hd0[0]); acc = fmaf(d, d, acc);
            d = xa.y - fmaxf(hd[1], hd0[1]); acc = fmaf(d, d, acc);
            d = xa.z - fmaxf(hd[2], hd0[2]); acc = fmaf(d, d, acc);
            d = xa.w - fmaxf(hd[3], hd0[3]); acc = fmaf(d, d, acc);
            d = xb.x - fmaxf(hd[4], hd0[4]); acc = fmaf(d, d, acc);
            d = xb.y - fmaxf(hd[5], hd0[5]); acc = fmaf(d, d, acc);
            d = xb.z - fmaxf(hd[6], hd0[6]); acc = fmaf(d, d, acc);
            d = xb.w - fmaxf(hd[7], hd0[7]); acc = fmaf(d, d, acc);
        }

        // ---- row a1 (a1 == IMG_H only at t=31 of the image-last chunk)
        float hd1[8];
        if (a1 < IMG_H) {
            float h1[9], E[9];
            mkh(c1a, c1b, h1);
            #pragma unroll
            for (int k = 0; k < 9; ++k) E[k] = fminf(h0[k], h1[k]);
            #pragma unroll
            for (int k = 0; k < 8; ++k) hd1[k] = fmaxf(E[k], E[k + 1]);
            #pragma unroll
            for (int k = 0; k < 9; ++k) hprev[k] = h1[k];
        } else {
            #pragma unroll
            for (int k = 0; k < 8; ++k) hd1[k] = hd0[k];   // hd[H] := hd[H-1]
        }
        {   // opened(a1-1) = max(hd0, hd1) vs x(a0) = c0
            float d;
            d = c0a.x - fmaxf(hd0[0], hd1[0]); acc = fmaf(d, d, acc);
            d = c0a.y - fmaxf(hd0[1], hd1[1]); acc = fmaf(d, d, acc);
            d = c0a.z - fmaxf(hd0[2], hd1[2]); acc = fmaf(d, d, acc);
            d = c0a.w - fmaxf(hd0[3], hd1[3]); acc = fmaf(d, d, acc);
            d = c0b.x - fmaxf(hd0[4], hd1[4]); acc = fmaf(d, d, acc);
            d = c0b.y - fmaxf(hd0[5], hd1[5]); acc = fmaf(d, d, acc);
            d = c0b.z - fmaxf(hd0[6], hd1[6]); acc = fmaf(d, d, acc);
            d = c0b.w - fmaxf(hd0[7], hd1[7]); acc = fmaf(d, d, acc);
        }

        #pragma unroll
        for (int k = 0; k < 8; ++k) hd[k] = hd1[k];
        xa = c1a; xb = c1b;
    }

    // wave shuffle reduce -> LDS across 2 waves -> one atomic per block
    #pragma unroll
    for (int off = 32; off > 0; off >>= 1)
        acc += __shfl_down(acc, off, 64);

    __shared__ float wsum[WPB];
    if (lane == 0) wsum[wid] = acc;
    __syncthreads();
    if (threadIdx.x == 0) {
        float sblk = wsum[0] + wsum[1];
        atomicAdd(out, sblk * (1.0f / 33554432.0f));   // / 2^25 -> mean
    }
}

extern "C" void kernel_launch(void* const* d_in, const int* in_sizes, int n_in,
                              void* d_out, int out_size, void* d_ws, size_t ws_size,
                              hipStream_t stream) {
    const float* X = (const float*)d_in[0];
    float* out = (float*)d_out;
    hipMemsetAsync(out, 0, sizeof(float), stream);
    opening_mse_kernel<<<NBLOCKS, THREADS, 0, stream>>>(X, out);
}